// Round 1
// baseline (10025.909 us; speedup 1.0000x reference)
//
#include <hip/hip_runtime.h>
#include <stdint.h>

#define BB 8
#define CC 256
#define JJ 16
#define LL 256
#define NBC 8192
#define NEL (BB*CC*JJ*LL)     // 8388608
#define NTOT 43296            // 32+256+2048+8192+32768
#define QT 32

__device__ __forceinline__ uint32_t ord_f32(float f) {
  uint32_t u = __float_as_uint(f);
  return (u & 0x80000000u) ? ~u : (u | 0x80000000u);
}

__device__ __forceinline__ float cubw(float x) {
  const float a = -0.75f;
  float ax = fabsf(x);
  if (ax <= 1.f) return ((a + 2.f) * ax - (a + 3.f)) * ax * ax + 1.f;
  if (ax < 2.f)  return a * (ax * ((ax - 5.f) * ax + 8.f) - 4.f);
  return 0.f;
}

// ---------------------------------------------------------------- init
__global__ void k_init(const float* __restrict__ f, float* __restrict__ f_rest,
                       unsigned long long* __restrict__ bkey,
                       uint32_t* __restrict__ counts, float* __restrict__ lacc) {
  int64_t i = (int64_t)blockIdx.x * blockDim.x + threadIdx.x;
  int64_t stride = (int64_t)gridDim.x * blockDim.x;
  for (int64_t x = i; x < NEL; x += stride) f_rest[x] = f[x];
  for (int64_t x = i; x < NTOT; x += stride) bkey[x] = 0xFFFFFFFFFFFFFFFFull;
  for (int64_t x = i; x < NBC; x += stride) counts[x] = 0u;
  if (i < 8) lacc[i] = 0.f;
}

// ---------------------------------------------------------------- cb_sq
__global__ void k_cbsq(const float* __restrict__ cb, float* __restrict__ cbsq) {
  int k = blockIdx.x * blockDim.x + threadIdx.x;
  if (k >= NBC) return;
  const float4* row = (const float4*)(cb + (size_t)k * CC);
  float s = 0.f;
  for (int i = 0; i < CC / 4; ++i) {
    float4 v = row[i];
    s += v.x * v.x + v.y * v.y + v.z * v.z + v.w * v.w;
  }
  cbsq[k] = s;
}

// ---------------------------------------------------------------- area pool -> rows [N][C]
// block per (b, c, s); thread = column l; coalesced row reads, LDS bin-reduce.
__global__ void k_pool(const float* __restrict__ f_rest, float* __restrict__ rows,
                       int sn, int tn) {
  int blk = blockIdx.x;
  int s = blk % sn;
  int c = (blk / sn) % CC;
  int b = blk / (sn * CC);
  int t = threadIdx.x;
  int pj = JJ / sn;
  int wbin = LL / tn;
  const float* base = f_rest + (((size_t)b * CC + c) * JJ + s * pj) * LL;
  float acc = 0.f;
  for (int j = 0; j < pj; ++j) acc += base[j * LL + t];
  __shared__ float lds[256];
  lds[t] = acc;
  __syncthreads();
  for (int off = wbin >> 1; off > 0; off >>= 1) {
    if ((t & (wbin - 1)) < off) lds[t] += lds[t + off];
    __syncthreads();
  }
  if ((t & (wbin - 1)) == 0) {
    int tb = t / wbin;
    rows[(((size_t)(b * sn + s)) * tn + tb) * CC + c] = lds[t] / (float)(pj * wbin);
  }
}

// ---------------------------------------------------------------- codebook argmin
// grid (qtiles, kchunks); block 256. QT=32 queries in LDS; thread owns code pair
// (k, k+256) per jp; score = cbsq[k] - 2*dot; packed-key atomicMin per query.
__global__ __launch_bounds__(256) void k_search(
    const float* __restrict__ qsrc, int transposed,
    const float* __restrict__ cb, const float* __restrict__ cbsq,
    unsigned long long* __restrict__ bkey, int pairs) {
  __shared__ float qlds[QT * CC];
  __shared__ unsigned long long red[4][QT];
  int tid = threadIdx.x;
  int qbase = blockIdx.x * QT;
  int KC = 512 * pairs;
  int kbase = blockIdx.y * KC;

  if (!transposed) {
    for (int i = tid; i < QT * CC; i += 256) qlds[i] = qsrc[(size_t)qbase * CC + i];
  } else {
    for (int i = tid; i < QT * CC; i += 256) {
      int r = i >> 8, c = i & 255;
      int n = qbase + r;
      int b = n >> 12, p = n & 4095;
      qlds[i] = qsrc[((size_t)(b * CC + c)) * 4096 + p];
    }
  }
  __syncthreads();

  unsigned long long bk[QT];
#pragma unroll
  for (int q = 0; q < QT; ++q) bk[q] = 0xFFFFFFFFFFFFFFFFull;

  const float4* ql = (const float4*)qlds;
  for (int jp = 0; jp < pairs; ++jp) {
    int k0 = kbase + jp * 512 + tid;
    int k1 = k0 + 256;
    const float4* r0 = (const float4*)(cb + (size_t)k0 * CC);
    const float4* r1 = (const float4*)(cb + (size_t)k1 * CC);
    float a0[QT], a1[QT];
#pragma unroll
    for (int q = 0; q < QT; ++q) { a0[q] = 0.f; a1[q] = 0.f; }
    for (int c16 = 0; c16 < CC / 16; ++c16) {
      float4 w0a = r0[c16 * 4 + 0], w0b = r0[c16 * 4 + 1], w0c = r0[c16 * 4 + 2], w0d = r0[c16 * 4 + 3];
      float4 w1a = r1[c16 * 4 + 0], w1b = r1[c16 * 4 + 1], w1c = r1[c16 * 4 + 2], w1d = r1[c16 * 4 + 3];
#pragma unroll
      for (int q = 0; q < QT; ++q) {
        float4 qa = ql[q * (CC / 4) + c16 * 4 + 0];
        float4 qb = ql[q * (CC / 4) + c16 * 4 + 1];
        float4 qc = ql[q * (CC / 4) + c16 * 4 + 2];
        float4 qd = ql[q * (CC / 4) + c16 * 4 + 3];
        a0[q] += w0a.x * qa.x + w0a.y * qa.y + w0a.z * qa.z + w0a.w * qa.w
               + w0b.x * qb.x + w0b.y * qb.y + w0b.z * qb.z + w0b.w * qb.w
               + w0c.x * qc.x + w0c.y * qc.y + w0c.z * qc.z + w0c.w * qc.w
               + w0d.x * qd.x + w0d.y * qd.y + w0d.z * qd.z + w0d.w * qd.w;
        a1[q] += w1a.x * qa.x + w1a.y * qa.y + w1a.z * qa.z + w1a.w * qa.w
               + w1b.x * qb.x + w1b.y * qb.y + w1b.z * qb.z + w1b.w * qb.w
               + w1c.x * qc.x + w1c.y * qc.y + w1c.z * qc.z + w1c.w * qc.w
               + w1d.x * qd.x + w1d.y * qd.y + w1d.z * qd.z + w1d.w * qd.w;
      }
    }
    float s0 = cbsq[k0], s1 = cbsq[k1];
#pragma unroll
    for (int q = 0; q < QT; ++q) {
      float d0 = s0 - 2.f * a0[q];
      float d1 = s1 - 2.f * a1[q];
      unsigned long long key0 = ((unsigned long long)ord_f32(d0) << 32) | (uint32_t)k0;
      unsigned long long key1 = ((unsigned long long)ord_f32(d1) << 32) | (uint32_t)k1;
      if (key0 < bk[q]) bk[q] = key0;
      if (key1 < bk[q]) bk[q] = key1;
    }
  }

  int lane = tid & 63, wv = tid >> 6;
#pragma unroll
  for (int q = 0; q < QT; ++q) {
    unsigned long long k = bk[q];
    for (int off = 32; off; off >>= 1) {
      uint32_t lo = (uint32_t)k, hi = (uint32_t)(k >> 32);
      uint32_t olo = __shfl_xor(lo, off, 64);
      uint32_t ohi = __shfl_xor(hi, off, 64);
      unsigned long long ok = ((unsigned long long)ohi << 32) | olo;
      if (ok < k) k = ok;
    }
    if (lane == 0) red[wv][q] = k;
  }
  __syncthreads();
  if (tid < QT) {
    unsigned long long k = red[0][tid];
    if (red[1][tid] < k) k = red[1][tid];
    if (red[2][tid] < k) k = red[2][tid];
    if (red[3][tid] < k) k = red[3][tid];
    atomicMin(&bkey[qbase + tid], k);
  }
}

// ---------------------------------------------------------------- gather + bicubic upsample
// block per (b,c,y); thread = x.
__global__ void k_upgather(const unsigned long long* __restrict__ bkey,
                           const float* __restrict__ cb,
                           float* __restrict__ h_up, int sn, int tn) {
  int blk = blockIdx.x;
  int y = blk % JJ;
  int c = (blk / JJ) % CC;
  int b = blk / (JJ * CC);
  int x = threadIdx.x;
  float val;
  if (sn == JJ) {  // last scale: identity
    int n = (b * JJ + y) * LL + x;
    int k = (uint32_t)bkey[n] & (NBC - 1);
    val = cb[(size_t)k * CC + c];
  } else {
    float cj = (y + 0.5f) * ((float)sn / (float)JJ) - 0.5f;
    float fj = floorf(cj);
    float tj = cj - fj;
    int ij = (int)fj;
    float wj[4]; int xj[4];
#pragma unroll
    for (int aa = 0; aa < 4; ++aa) {
      wj[aa] = cubw(tj - (float)(aa - 1));
      int id = ij + aa - 1;
      xj[aa] = min(max(id, 0), sn - 1);
    }
    float clx = (x + 0.5f) * ((float)tn / (float)LL) - 0.5f;
    float fl = floorf(clx);
    float tl = clx - fl;
    int il = (int)fl;
    float wl[4]; int xl[4];
#pragma unroll
    for (int ee = 0; ee < 4; ++ee) {
      wl[ee] = cubw(tl - (float)(ee - 1));
      int id = il + ee - 1;
      xl[ee] = min(max(id, 0), tn - 1);
    }
    val = 0.f;
#pragma unroll
    for (int aa = 0; aa < 4; ++aa) {
      float rowv = 0.f;
#pragma unroll
      for (int ee = 0; ee < 4; ++ee) {
        int n = (b * sn + xj[aa]) * tn + xl[ee];
        int k = (uint32_t)bkey[n] & (NBC - 1);
        rowv += wl[ee] * cb[(size_t)k * CC + c];
      }
      val += wj[aa] * rowv;
    }
  }
  h_up[(((size_t)b * CC + c) * JJ + y) * LL + x] = val;
}

// ---------------------------------------------------------------- conv3x3 + phi mix + residual update + loss
// block: (b, y, xt(2), cot(4)); tile co=64 x=128; thread = 4co x 8x.
#define CO_T 64
#define X_T 128
#define CI_T 16
__global__ __launch_bounds__(256) void k_conv_update(
    const float* __restrict__ h_up, const float* __restrict__ w,
    const float* __restrict__ bias, float* __restrict__ f_rest,
    float* __restrict__ lacc, int si) {
  __shared__ float in_lds[CI_T * 3 * 132];
  __shared__ float w_lds[CI_T * 9 * 68];
  __shared__ float redl[4];
  int tid = threadIdx.x;
  int blk = blockIdx.x;
  int cot = blk & 3;
  int xt  = (blk >> 2) & 1;
  int y   = (blk >> 3) & 15;
  int b   = blk >> 7;
  int co0 = cot * CO_T;
  int x0  = xt * X_T;
  int co_g = tid >> 4;  // 0..15 -> 4 consecutive co
  int x_g  = tid & 15;  // 0..15 -> 8 consecutive x
  float acc[4][8];
#pragma unroll
  for (int i = 0; i < 4; ++i)
#pragma unroll
    for (int j = 0; j < 8; ++j) acc[i][j] = 0.f;

  for (int ci0 = 0; ci0 < CC; ci0 += CI_T) {
    __syncthreads();
    for (int e = tid; e < CI_T * 3 * 130; e += 256) {
      int ci = e / 390;
      int r  = e % 390;
      int ky = r / 130;
      int xc = r % 130;
      int gy = y - 1 + ky;
      int gx = x0 - 1 + xc;
      float v = 0.f;
      if (gy >= 0 && gy < JJ && gx >= 0 && gx < LL)
        v = h_up[(((size_t)b * CC + ci0 + ci) * JJ + gy) * LL + gx];
      in_lds[(ci * 3 + ky) * 132 + xc] = v;
    }
    for (int e = tid; e < CO_T * 144; e += 256) {
      int co = e / 144;
      int r  = e % 144;
      w_lds[r * 68 + co] = w[((size_t)(co0 + co) * CC + ci0) * 9 + r];
    }
    __syncthreads();
    for (int ci = 0; ci < CI_T; ++ci) {
#pragma unroll
      for (int ky = 0; ky < 3; ++ky) {
        const float* row = &in_lds[(ci * 3 + ky) * 132 + x_g * 8];
        float4 v0 = *(const float4*)(row);
        float4 v1 = *(const float4*)(row + 4);
        float4 v2 = *(const float4*)(row + 8);
        float iv[12] = {v0.x, v0.y, v0.z, v0.w, v1.x, v1.y, v1.z, v1.w,
                        v2.x, v2.y, v2.z, v2.w};
#pragma unroll
        for (int kx = 0; kx < 3; ++kx) {
          float4 w4 = *(const float4*)&w_lds[(ci * 9 + ky * 3 + kx) * 68 + co_g * 4];
#pragma unroll
          for (int xx = 0; xx < 8; ++xx) {
            float inv = iv[xx + kx];
            acc[0][xx] += w4.x * inv;
            acc[1][xx] += w4.y * inv;
            acc[2][xx] += w4.z * inv;
            acc[3][xx] += w4.w * inv;
          }
        }
      }
    }
  }

  float lsum = 0.f;
#pragma unroll
  for (int i = 0; i < 4; ++i) {
    int co = co0 + co_g * 4 + i;
    float bv = bias[co];
#pragma unroll
    for (int j = 0; j < 8; ++j) {
      int x = x0 + x_g * 8 + j;
      size_t g = (((size_t)b * CC + co) * JJ + y) * LL + x;
      float h = h_up[g];
      float o = 0.5f * h + 0.5f * (acc[i][j] + bv);
      float fr = f_rest[g] - o;
      f_rest[g] = fr;
      lsum += fr * fr;
    }
  }
  for (int off = 32; off; off >>= 1) lsum += __shfl_xor(lsum, off, 64);
  if ((tid & 63) == 0) redl[tid >> 6] = lsum;
  __syncthreads();
  if (tid == 0) atomicAdd(&lacc[si], redl[0] + redl[1] + redl[2] + redl[3]);
}

// ---------------------------------------------------------------- histogram over all indices
__global__ void k_hist(const unsigned long long* __restrict__ bkey,
                       uint32_t* __restrict__ counts) {
  int i = blockIdx.x * 256 + threadIdx.x;
  if (i < NTOT) atomicAdd(&counts[(uint32_t)bkey[i] & (NBC - 1)], 1u);
}

// ---------------------------------------------------------------- f_hat = f - f_rest
__global__ void k_finalout(const float* __restrict__ f,
                           const float* __restrict__ f_rest,
                           float* __restrict__ out) {
  size_t i = (size_t)blockIdx.x * 256 + threadIdx.x;
  if (i < NEL) out[i] = f[i] - f_rest[i];
}

// ---------------------------------------------------------------- loss + perplexity scalars
__global__ void k_scalars(const uint32_t* __restrict__ counts,
                          const float* __restrict__ lacc,
                          float* __restrict__ out) {
  __shared__ float red[4];
  int tid = threadIdx.x;
  float s = 0.f;
  for (int i = tid; i < NBC; i += 256) {
    float p = (float)counts[i] * (1.0f / (float)NTOT);
    s += p * logf(p + 1e-7f);
  }
  for (int off = 32; off; off >>= 1) s += __shfl_xor(s, off, 64);
  if ((tid & 63) == 0) red[tid >> 6] = s;
  __syncthreads();
  if (tid == 0) {
    float ent = red[0] + red[1] + red[2] + red[3];
    out[NEL + 1] = expf(-ent);
    float l = 0.f;
    for (int i = 0; i < 5; ++i) l += lacc[i];
    out[NEL] = l * (1.0f / (float)NEL / 5.0f);
  }
}

extern "C" void kernel_launch(void* const* d_in, const int* in_sizes, int n_in,
                              void* d_out, int out_size, void* d_ws, size_t ws_size,
                              hipStream_t stream) {
  const float* f  = (const float*)d_in[0];
  const float* cb = (const float*)d_in[1];
  const float* pw = (const float*)d_in[2];
  const float* pb = (const float*)d_in[3];
  float* out = (float*)d_out;

  char* ws = (char*)d_ws;
  size_t off = 0;
  auto alloc = [&](size_t bytes) {
    void* p = ws + off;
    off += (bytes + 255) & ~(size_t)255;
    return p;
  };
  float* f_rest = (float*)alloc((size_t)NEL * 4);
  float* h_up   = (float*)alloc((size_t)NEL * 4);
  float* rows   = (float*)alloc((size_t)8192 * 256 * 4);  // largest pooled scale (si=3)
  float* cbsq   = (float*)alloc((size_t)NBC * 4);
  unsigned long long* bkey = (unsigned long long*)alloc((size_t)NTOT * 8);
  uint32_t* counts = (uint32_t*)alloc((size_t)NBC * 4);
  float* lacc = (float*)alloc(8 * 4);

  k_init<<<2048, 256, 0, stream>>>(f, f_rest, bkey, counts, lacc);
  k_cbsq<<<NBC / 256, 256, 0, stream>>>(cb, cbsq);

  const int SNs[5]   = {1, 2, 4, 8, 16};
  const int TNs[5]   = {4, 16, 64, 128, 256};
  const int PHI[5]   = {0, 1, 1, 2, 3};
  const int PAIRS[5] = {1, 1, 2, 2, 4};  // codes/thread = 2*pairs; KC = 512*pairs
  int offs = 0;
  for (int si = 0; si < 5; ++si) {
    int sn = SNs[si], tn = TNs[si];
    int N = BB * sn * tn;
    unsigned long long* bk = bkey + offs;
    const float* qsrc;
    int transposed;
    if (si < 4) {
      k_pool<<<BB * CC * sn, 256, 0, stream>>>(f_rest, rows, sn, tn);
      qsrc = rows;
      transposed = 0;
    } else {
      qsrc = f_rest;
      transposed = 1;
    }
    int qtiles = N / QT;
    int kchunks = NBC / (512 * PAIRS[si]);
    dim3 g(qtiles, kchunks);
    k_search<<<g, 256, 0, stream>>>(qsrc, transposed, cb, cbsq, bk, PAIRS[si]);
    k_upgather<<<BB * CC * JJ, LL, 0, stream>>>(bk, cb, h_up, sn, tn);
    k_conv_update<<<1024, 256, 0, stream>>>(h_up, pw + (size_t)PHI[si] * CC * CC * 9,
                                            pb + (size_t)PHI[si] * CC, f_rest, lacc, si);
    offs += N;
  }
  k_hist<<<(NTOT + 255) / 256, 256, 0, stream>>>(bkey, counts);
  k_finalout<<<NEL / 256, 256, 0, stream>>>(f, f_rest, out);
  k_scalars<<<1, 256, 0, stream>>>(counts, lacc, out);
}

// Round 2
// 6474.436 us; speedup vs baseline: 1.5485x; 1.5485x over previous
//
#include <hip/hip_runtime.h>
#include <stdint.h>

#define BB 8
#define CC 256
#define JJ 16
#define LL 256
#define NPIX 32768            // B*J*L
#define NEL (BB*CC*JJ*LL)     // 8388608
#define NBC 8192
#define NTOT 43296            // 32+256+2048+8192+32768
#define QT 32

typedef unsigned short u16;
typedef short short8 __attribute__((ext_vector_type(8)));
typedef float floatx4 __attribute__((ext_vector_type(4)));

__device__ __forceinline__ uint32_t ord_f32(float f) {
  uint32_t u = __float_as_uint(f);
  return (u & 0x80000000u) ? ~u : (u | 0x80000000u);
}

__device__ __forceinline__ float cubw(float x) {
  const float a = -0.75f;
  float ax = fabsf(x);
  if (ax <= 1.f) return ((a + 2.f) * ax - (a + 3.f)) * ax * ax + 1.f;
  if (ax < 2.f)  return a * (ax * ((ax - 5.f) * ax + 8.f) - 4.f);
  return 0.f;
}

__device__ __forceinline__ u16 bf16h(float x) {
  uint32_t u = __float_as_uint(x);
  return (u16)((u + 0x7FFFu + ((u >> 16) & 1u)) >> 16);   // RNE
}
__device__ __forceinline__ float bf16f(u16 h) {
  return __uint_as_float(((uint32_t)h) << 16);
}

// ---------------------------------------------------------------- init small buffers
__global__ void k_init(unsigned long long* __restrict__ bkey,
                       uint32_t* __restrict__ counts, float* __restrict__ lacc) {
  int i = blockIdx.x * 256 + threadIdx.x;
  int stride = gridDim.x * 256;
  for (int x = i; x < NTOT; x += stride) bkey[x] = 0xFFFFFFFFFFFFFFFFull;
  for (int x = i; x < NBC; x += stride) counts[x] = 0u;
  if (i < 8) lacc[i] = 0.f;
}

// ---------------------------------------------------------------- f [B,C,J,L] -> pm [p][c]
__global__ void k_f2pm(const float* __restrict__ f, float* __restrict__ pm) {
  __shared__ float t[64][65];
  int tid = threadIdx.x;
  int px0 = blockIdx.x * 64, c0 = blockIdx.y * 64;
  int b = px0 >> 12, y = (px0 >> 8) & 15, x0 = px0 & 255;
#pragma unroll
  for (int it = 0; it < 4; ++it) {
    int slot = it * 256 + tid;
    int c = slot >> 4, q = (slot & 15) * 4;
    float4 v = *(const float4*)(f + (((size_t)(b * 256 + c0 + c)) * 16 + y) * 256 + x0 + q);
    t[c][q] = v.x; t[c][q + 1] = v.y; t[c][q + 2] = v.z; t[c][q + 3] = v.w;
  }
  __syncthreads();
#pragma unroll
  for (int it = 0; it < 4; ++it) {
    int slot = it * 256 + tid;
    int i = slot >> 4, q = (slot & 15) * 4;
    float4 v;
    v.x = t[q + 0][i]; v.y = t[q + 1][i]; v.z = t[q + 2][i]; v.w = t[q + 3][i];
    *(float4*)(pm + (size_t)(px0 + i) * 256 + c0 + q) = v;
  }
}

// ---------------------------------------------------------------- out = f - pm (transpose back)
__global__ void k_out(const float* __restrict__ f, const float* __restrict__ pm,
                      float* __restrict__ out) {
  __shared__ float t[64][65];
  int tid = threadIdx.x;
  int px0 = blockIdx.x * 64, c0 = blockIdx.y * 64;
  int b = px0 >> 12, y = (px0 >> 8) & 15, x0 = px0 & 255;
#pragma unroll
  for (int it = 0; it < 4; ++it) {
    int slot = it * 256 + tid;
    int i = slot >> 4, q = (slot & 15) * 4;
    float4 v = *(const float4*)(pm + (size_t)(px0 + i) * 256 + c0 + q);
    t[q + 0][i] = v.x; t[q + 1][i] = v.y; t[q + 2][i] = v.z; t[q + 3][i] = v.w;
  }
  __syncthreads();
#pragma unroll
  for (int it = 0; it < 4; ++it) {
    int slot = it * 256 + tid;
    int c = slot >> 4, q = (slot & 15) * 4;
    size_t g = (((size_t)(b * 256 + c0 + c)) * 16 + y) * 256 + x0 + q;
    float4 fv = *(const float4*)(f + g);
    float4 o;
    o.x = fv.x - t[c][q + 0]; o.y = fv.y - t[c][q + 1];
    o.z = fv.z - t[c][q + 2]; o.w = fv.w - t[c][q + 3];
    *(float4*)(out + g) = o;
  }
}

// ---------------------------------------------------------------- cb_sq
__global__ void k_cbsq(const float* __restrict__ cb, float* __restrict__ cbsq) {
  int k = blockIdx.x * blockDim.x + threadIdx.x;
  if (k >= NBC) return;
  const float4* row = (const float4*)(cb + (size_t)k * CC);
  float s = 0.f;
  for (int i = 0; i < CC / 4; ++i) {
    float4 v = row[i];
    s += v.x * v.x + v.y * v.y + v.z * v.z + v.w * v.w;
  }
  cbsq[k] = s;
}

// ---------------------------------------------------------------- weight split/transpose prep
// Whi/Wlo[(phi*9+s)*256 + co][ci] bf16
__global__ void k_wprep(const float* __restrict__ pw, u16* __restrict__ Whi,
                        u16* __restrict__ Wlo) {
  int bx = blockIdx.x;          // (phi*9+s)*256 + co
  int co = bx & 255;
  int ps = bx >> 8;             // phi*9+s
  int phi = ps / 9, s = ps % 9;
  int ci = threadIdx.x;
  float v = pw[(((size_t)(phi * 256 + co)) * 256 + ci) * 9 + s];
  u16 h = bf16h(v);
  Whi[(size_t)bx * 256 + ci] = h;
  Wlo[(size_t)bx * 256 + ci] = bf16h(v - bf16f(h));
}

// ---------------------------------------------------------------- pooling (pixel-major), 2-phase
__global__ void k_poolpart(const float* __restrict__ pm, float* __restrict__ part,
                           int sn, int tn, int pj, int wl, int K, int ppk) {
  int n = blockIdx.x, kk = blockIdx.y, c = threadIdx.x;
  int b = n / (sn * tn);
  int s = (n / tn) % sn;
  int t = n % tn;
  float acc = 0.f;
  for (int q = kk * ppk; q < (kk + 1) * ppk; ++q) {
    int yy = s * pj + q / wl;
    int xx = t * wl + q % wl;
    size_t p = (size_t)b * 4096 + (size_t)yy * 256 + xx;
    acc += pm[p * 256 + c];
  }
  part[((size_t)n * K + kk) * 256 + c] = acc;
}

__global__ void k_poolfin(const float* __restrict__ part, float* __restrict__ rows,
                          int K, float inv) {
  int n = blockIdx.x, c = threadIdx.x;
  float s = 0.f;
  for (int kk = 0; kk < K; ++kk) s += part[((size_t)n * K + kk) * 256 + c];
  rows[(size_t)n * 256 + c] = s * inv;
}

// ---------------------------------------------------------------- codebook argmin (fp32)
__global__ __launch_bounds__(256) void k_search(
    const float* __restrict__ qsrc,
    const float* __restrict__ cb, const float* __restrict__ cbsq,
    unsigned long long* __restrict__ bkey, int pairs) {
  __shared__ float qlds[QT * CC];
  __shared__ unsigned long long red[4][QT];
  int tid = threadIdx.x;
  int qbase = blockIdx.x * QT;
  int KC = 512 * pairs;
  int kbase = blockIdx.y * KC;

  for (int i = tid; i < QT * CC; i += 256) qlds[i] = qsrc[(size_t)qbase * CC + i];
  __syncthreads();

  unsigned long long bk[QT];
#pragma unroll
  for (int q = 0; q < QT; ++q) bk[q] = 0xFFFFFFFFFFFFFFFFull;

  const float4* ql = (const float4*)qlds;
  for (int jp = 0; jp < pairs; ++jp) {
    int k0 = kbase + jp * 512 + tid;
    int k1 = k0 + 256;
    const float4* r0 = (const float4*)(cb + (size_t)k0 * CC);
    const float4* r1 = (const float4*)(cb + (size_t)k1 * CC);
    float a0[QT], a1[QT];
#pragma unroll
    for (int q = 0; q < QT; ++q) { a0[q] = 0.f; a1[q] = 0.f; }
    for (int c16 = 0; c16 < CC / 16; ++c16) {
      float4 w0a = r0[c16 * 4 + 0], w0b = r0[c16 * 4 + 1], w0c = r0[c16 * 4 + 2], w0d = r0[c16 * 4 + 3];
      float4 w1a = r1[c16 * 4 + 0], w1b = r1[c16 * 4 + 1], w1c = r1[c16 * 4 + 2], w1d = r1[c16 * 4 + 3];
#pragma unroll
      for (int q = 0; q < QT; ++q) {
        float4 qa = ql[q * (CC / 4) + c16 * 4 + 0];
        float4 qb = ql[q * (CC / 4) + c16 * 4 + 1];
        float4 qc = ql[q * (CC / 4) + c16 * 4 + 2];
        float4 qd = ql[q * (CC / 4) + c16 * 4 + 3];
        a0[q] += w0a.x * qa.x + w0a.y * qa.y + w0a.z * qa.z + w0a.w * qa.w
               + w0b.x * qb.x + w0b.y * qb.y + w0b.z * qb.z + w0b.w * qb.w
               + w0c.x * qc.x + w0c.y * qc.y + w0c.z * qc.z + w0c.w * qc.w
               + w0d.x * qd.x + w0d.y * qd.y + w0d.z * qd.z + w0d.w * qd.w;
        a1[q] += w1a.x * qa.x + w1a.y * qa.y + w1a.z * qa.z + w1a.w * qa.w
               + w1b.x * qb.x + w1b.y * qb.y + w1b.z * qb.z + w1b.w * qb.w
               + w1c.x * qc.x + w1c.y * qc.y + w1c.z * qc.z + w1c.w * qc.w
               + w1d.x * qd.x + w1d.y * qd.y + w1d.z * qd.z + w1d.w * qd.w;
      }
    }
    float s0 = cbsq[k0], s1 = cbsq[k1];
#pragma unroll
    for (int q = 0; q < QT; ++q) {
      float d0 = s0 - 2.f * a0[q];
      float d1 = s1 - 2.f * a1[q];
      unsigned long long key0 = ((unsigned long long)ord_f32(d0) << 32) | (uint32_t)k0;
      unsigned long long key1 = ((unsigned long long)ord_f32(d1) << 32) | (uint32_t)k1;
      if (key0 < bk[q]) bk[q] = key0;
      if (key1 < bk[q]) bk[q] = key1;
    }
  }

  int lane = tid & 63, wv = tid >> 6;
#pragma unroll
  for (int q = 0; q < QT; ++q) {
    unsigned long long k = bk[q];
    for (int off = 32; off; off >>= 1) {
      uint32_t lo = (uint32_t)k, hi = (uint32_t)(k >> 32);
      uint32_t olo = __shfl_xor(lo, off, 64);
      uint32_t ohi = __shfl_xor(hi, off, 64);
      unsigned long long ok = ((unsigned long long)ohi << 32) | olo;
      if (ok < k) k = ok;
    }
    if (lane == 0) red[wv][q] = k;
  }
  __syncthreads();
  if (tid < QT) {
    unsigned long long k = red[0][tid];
    if (red[1][tid] < k) k = red[1][tid];
    if (red[2][tid] < k) k = red[2][tid];
    if (red[3][tid] < k) k = red[3][tid];
    atomicMin(&bkey[qbase + tid], k);
  }
}

// ---------------------------------------------------------------- gather + bicubic up -> split bf16 H
__global__ void k_upgather(const unsigned long long* __restrict__ bkey,
                           const float* __restrict__ cb,
                           u16* __restrict__ Hhi, u16* __restrict__ Hlo,
                           int sn, int tn, int last) {
  __shared__ int sidx[8][16];
  __shared__ float swgt[8][16];
  int tid = threadIdx.x;
  int p0 = blockIdx.x * 8;
  if (!last) {
    if (tid < 128) {
      int pp = tid >> 4, tap = tid & 15;
      int aa = tap >> 2, ee = tap & 3;
      int p = p0 + pp;
      int b = p >> 12, y = (p >> 8) & 15, x = p & 255;
      float cj = (y + 0.5f) * ((float)sn / 16.f) - 0.5f;
      float fj = floorf(cj); float tj = cj - fj; int ij = (int)fj;
      float wj = cubw(tj - (float)(aa - 1));
      int xj = min(max(ij + aa - 1, 0), sn - 1);
      float cl = (x + 0.5f) * ((float)tn / 256.f) - 0.5f;
      float fl = floorf(cl); float tl = cl - fl; int il = (int)fl;
      float wle = cubw(tl - (float)(ee - 1));
      int xl = min(max(il + ee - 1, 0), tn - 1);
      int n = (b * sn + xj) * tn + xl;
      sidx[pp][tap] = (int)((uint32_t)bkey[n] & (NBC - 1));
      swgt[pp][tap] = wj * wle;
    }
  } else {
    if (tid < 8) sidx[tid][0] = (int)((uint32_t)bkey[p0 + tid] & (NBC - 1));
  }
  __syncthreads();
  int c = tid;
  for (int pp = 0; pp < 8; ++pp) {
    float val;
    if (last) {
      val = cb[(size_t)sidx[pp][0] * 256 + c];
    } else {
      val = 0.f;
#pragma unroll
      for (int tap = 0; tap < 16; ++tap)
        val += swgt[pp][tap] * cb[(size_t)sidx[pp][tap] * 256 + c];
    }
    u16 h = bf16h(val);
    u16 l = bf16h(val - bf16f(h));
    size_t g = (size_t)(p0 + pp) * 256 + c;
    Hhi[g] = h;
    Hlo[g] = l;
  }
}

// ---------------------------------------------------------------- conv3x3 as split-bf16 MFMA implicit GEMM
// block = 128 px x 128 co; 4 waves in 2x2; wave = 64x64 via 16x16x32 bf16 MFMA.
// K-loop: 9 shifts x 8 ci-chunks of 32. LDS rows padded to 40 (2-way bank alias = free).
__global__ __launch_bounds__(256) void k_conv(
    const u16* __restrict__ Hhi, const u16* __restrict__ Hlo,
    const u16* __restrict__ Wh, const u16* __restrict__ Wl,
    const float* __restrict__ bias, float* __restrict__ pm,
    float* __restrict__ lacc, int si) {
  __shared__ __align__(16) u16 Ah[128 * 40];
  __shared__ __align__(16) u16 Al[128 * 40];
  __shared__ __align__(16) u16 Bh[128 * 40];
  __shared__ __align__(16) u16 Bl[128 * 40];
  __shared__ float redl[4];
  int tid = threadIdx.x;
  int mt = blockIdx.x >> 1, nt = blockIdx.x & 1;
  int px0 = mt * 128;
  int b4096 = px0 & ~4095;
  int y = (px0 >> 8) & 15;
  int x0 = px0 & 255;
  int co0 = nt * 128;
  int wid = tid >> 6, lane = tid & 63;
  int wm = wid & 1, wn = wid >> 1;
  int lm = lane & 15, quad = lane >> 4, k0 = quad * 8;

  floatx4 acc[4][4];
#pragma unroll
  for (int i = 0; i < 4; ++i)
#pragma unroll
    for (int j = 0; j < 4; ++j) acc[i][j] = (floatx4){0.f, 0.f, 0.f, 0.f};

  for (int s = 0; s < 9; ++s) {
    int dy = s / 3 - 1, dx = s % 3 - 1;
    int ys = y + dy;
    if (ys < 0 || ys > 15) continue;       // wave-uniform skip
    const u16* wbh = Wh + (size_t)s * 65536;
    const u16* wbl = Wl + (size_t)s * 65536;
    for (int ci0 = 0; ci0 < 256; ci0 += 32) {
      __syncthreads();
#pragma unroll
      for (int it = 0; it < 2; ++it) {
        int slot = tid + it * 256;
        int pxl = slot >> 2, ch = (slot & 3) * 8;
        int xs = x0 + pxl + dx;
        uint4 vh = {0, 0, 0, 0}, vl = {0, 0, 0, 0};
        if (xs >= 0 && xs < 256) {
          size_t g = ((size_t)(b4096 + ys * 256 + xs)) * 256 + ci0 + ch;
          vh = *(const uint4*)(Hhi + g);
          vl = *(const uint4*)(Hlo + g);
        }
        *(uint4*)&Ah[pxl * 40 + ch] = vh;
        *(uint4*)&Al[pxl * 40 + ch] = vl;
        size_t gw = (size_t)(co0 + pxl) * 256 + ci0 + ch;
        *(uint4*)&Bh[pxl * 40 + ch] = *(const uint4*)(wbh + gw);
        *(uint4*)&Bl[pxl * 40 + ch] = *(const uint4*)(wbl + gw);
      }
      __syncthreads();
      short8 ah[4], al[4], bh[4], bl[4];
#pragma unroll
      for (int mi = 0; mi < 4; ++mi) {
        int r = wm * 64 + mi * 16 + lm;
        ah[mi] = *(const short8*)&Ah[r * 40 + k0];
        al[mi] = *(const short8*)&Al[r * 40 + k0];
      }
#pragma unroll
      for (int ni = 0; ni < 4; ++ni) {
        int r = wn * 64 + ni * 16 + lm;
        bh[ni] = *(const short8*)&Bh[r * 40 + k0];
        bl[ni] = *(const short8*)&Bl[r * 40 + k0];
      }
#pragma unroll
      for (int mi = 0; mi < 4; ++mi)
#pragma unroll
        for (int ni = 0; ni < 4; ++ni) {
          acc[mi][ni] = __builtin_amdgcn_mfma_f32_16x16x32_bf16(ah[mi], bh[ni], acc[mi][ni], 0, 0, 0);
          acc[mi][ni] = __builtin_amdgcn_mfma_f32_16x16x32_bf16(ah[mi], bl[ni], acc[mi][ni], 0, 0, 0);
          acc[mi][ni] = __builtin_amdgcn_mfma_f32_16x16x32_bf16(al[mi], bh[ni], acc[mi][ni], 0, 0, 0);
        }
    }
  }

  float lsum = 0.f;
#pragma unroll
  for (int mi = 0; mi < 4; ++mi) {
#pragma unroll
    for (int ni = 0; ni < 4; ++ni) {
      int co = co0 + wn * 64 + ni * 16 + lm;
      float bv = bias[co];
#pragma unroll
      for (int r = 0; r < 4; ++r) {
        int px = px0 + wm * 64 + mi * 16 + quad * 4 + r;
        size_t g = (size_t)px * 256 + co;
        float h = bf16f(Hhi[g]) + bf16f(Hlo[g]);
        float o = 0.5f * h + 0.5f * (acc[mi][ni][r] + bv);
        float fr = pm[g] - o;
        pm[g] = fr;
        lsum += fr * fr;
      }
    }
  }
  for (int off = 32; off; off >>= 1) lsum += __shfl_xor(lsum, off, 64);
  if (lane == 0) redl[wid] = lsum;
  __syncthreads();
  if (tid == 0) atomicAdd(&lacc[si], redl[0] + redl[1] + redl[2] + redl[3]);
}

// ---------------------------------------------------------------- histogram
__global__ void k_hist(const unsigned long long* __restrict__ bkey,
                       uint32_t* __restrict__ counts) {
  int i = blockIdx.x * 256 + threadIdx.x;
  if (i < NTOT) atomicAdd(&counts[(uint32_t)bkey[i] & (NBC - 1)], 1u);
}

// ---------------------------------------------------------------- loss + perplexity scalars
__global__ void k_scalars(const uint32_t* __restrict__ counts,
                          const float* __restrict__ lacc,
                          float* __restrict__ out) {
  __shared__ float red[4];
  int tid = threadIdx.x;
  float s = 0.f;
  for (int i = tid; i < NBC; i += 256) {
    float p = (float)counts[i] * (1.0f / (float)NTOT);
    s += p * logf(p + 1e-7f);
  }
  for (int off = 32; off; off >>= 1) s += __shfl_xor(s, off, 64);
  if ((tid & 63) == 0) red[tid >> 6] = s;
  __syncthreads();
  if (tid == 0) {
    float ent = red[0] + red[1] + red[2] + red[3];
    out[NEL + 1] = expf(-ent);
    float l = 0.f;
    for (int i = 0; i < 5; ++i) l += lacc[i];
    out[NEL] = l * (1.0f / (float)NEL / 5.0f);
  }
}

extern "C" void kernel_launch(void* const* d_in, const int* in_sizes, int n_in,
                              void* d_out, int out_size, void* d_ws, size_t ws_size,
                              hipStream_t stream) {
  const float* f  = (const float*)d_in[0];
  const float* cb = (const float*)d_in[1];
  const float* pw = (const float*)d_in[2];
  const float* pb = (const float*)d_in[3];
  float* out = (float*)d_out;

  char* ws = (char*)d_ws;
  size_t off = 0;
  auto alloc = [&](size_t bytes) {
    void* p = ws + off;
    off += (bytes + 255) & ~(size_t)255;
    return p;
  };
  float* pm    = (float*)alloc((size_t)NEL * 4);            // f_rest, pixel-major [p][c]
  u16*   Hhi   = (u16*)alloc((size_t)NEL * 2);
  u16*   Hlo   = (u16*)alloc((size_t)NEL * 2);
  float* rows  = (float*)alloc((size_t)8192 * 256 * 4);
  float* part  = (float*)alloc((size_t)8192 * 256 * 4);
  u16*   Whi   = (u16*)alloc((size_t)4 * 9 * 65536 * 2);
  u16*   Wlo   = (u16*)alloc((size_t)4 * 9 * 65536 * 2);
  float* cbsq  = (float*)alloc((size_t)NBC * 4);
  unsigned long long* bkey = (unsigned long long*)alloc((size_t)NTOT * 8);
  uint32_t* counts = (uint32_t*)alloc((size_t)NBC * 4);
  float* lacc = (float*)alloc(8 * 4);

  k_init<<<256, 256, 0, stream>>>(bkey, counts, lacc);
  k_f2pm<<<dim3(NPIX / 64, 4), 256, 0, stream>>>(f, pm);
  k_cbsq<<<NBC / 256, 256, 0, stream>>>(cb, cbsq);
  k_wprep<<<4 * 9 * 256, 256, 0, stream>>>(pw, Whi, Wlo);

  const int SNs[5]   = {1, 2, 4, 8, 16};
  const int TNs[5]   = {4, 16, 64, 128, 256};
  const int PHI[5]   = {0, 1, 1, 2, 3};
  const int PAIRS[5] = {1, 1, 2, 2, 4};
  const int Ks[5]    = {16, 8, 2, 1, 1};
  int offs = 0;
  for (int si = 0; si < 5; ++si) {
    int sn = SNs[si], tn = TNs[si];
    int N = BB * sn * tn;
    int pj = JJ / sn, wl = LL / tn;
    unsigned long long* bk = bkey + offs;
    const float* qsrc;
    if (si < 4) {
      int K = Ks[si], npx = pj * wl;
      k_poolpart<<<dim3(N, K), 256, 0, stream>>>(pm, part, sn, tn, pj, wl, K, npx / K);
      k_poolfin<<<N, 256, 0, stream>>>(part, rows, K, 1.0f / (float)npx);
      qsrc = rows;
    } else {
      qsrc = pm;   // pixel-major residual IS the query matrix
    }
    dim3 g(N / QT, NBC / (512 * PAIRS[si]));
    k_search<<<g, 256, 0, stream>>>(qsrc, cb, cbsq, bk, PAIRS[si]);
    k_upgather<<<NPIX / 8, 256, 0, stream>>>(bk, cb, Hhi, Hlo, sn, tn, si == 4);
    k_conv<<<512, 256, 0, stream>>>(Hhi, Hlo,
                                    Whi + (size_t)PHI[si] * 9 * 65536,
                                    Wlo + (size_t)PHI[si] * 9 * 65536,
                                    pb + (size_t)PHI[si] * 256, pm, lacc, si);
    offs += N;
  }
  k_hist<<<(NTOT + 255) / 256, 256, 0, stream>>>(bkey, counts);
  k_out<<<dim3(NPIX / 64, 4), 256, 0, stream>>>(f, pm, out);
  k_scalars<<<1, 256, 0, stream>>>(counts, lacc, out);
}

// Round 3
// 1588.001 us; speedup vs baseline: 6.3135x; 4.0771x over previous
//
#include <hip/hip_runtime.h>
#include <stdint.h>

#define BB 8
#define CC 256
#define JJ 16
#define LL 256
#define NPIX 32768            // B*J*L
#define NEL (BB*CC*JJ*LL)     // 8388608
#define NBC 8192
#define NTOT 43296            // 32+256+2048+8192+32768

typedef unsigned short u16;
typedef short short8 __attribute__((ext_vector_type(8)));
typedef float floatx4 __attribute__((ext_vector_type(4)));

__device__ __forceinline__ uint32_t ord_f32(float f) {
  uint32_t u = __float_as_uint(f);
  return (u & 0x80000000u) ? ~u : (u | 0x80000000u);
}

__device__ __forceinline__ float cubw(float x) {
  const float a = -0.75f;
  float ax = fabsf(x);
  if (ax <= 1.f) return ((a + 2.f) * ax - (a + 3.f)) * ax * ax + 1.f;
  if (ax < 2.f)  return a * (ax * ((ax - 5.f) * ax + 8.f) - 4.f);
  return 0.f;
}

__device__ __forceinline__ u16 bf16h(float x) {
  uint32_t u = __float_as_uint(x);
  return (u16)((u + 0x7FFFu + ((u >> 16) & 1u)) >> 16);   // RNE
}
__device__ __forceinline__ float bf16f(u16 h) {
  return __uint_as_float(((uint32_t)h) << 16);
}

// ---------------------------------------------------------------- init small buffers
__global__ void k_init(unsigned long long* __restrict__ bkey,
                       uint32_t* __restrict__ counts, float* __restrict__ lacc) {
  int i = blockIdx.x * 256 + threadIdx.x;
  int stride = gridDim.x * 256;
  for (int x = i; x < NTOT; x += stride) bkey[x] = 0xFFFFFFFFFFFFFFFFull;
  for (int x = i; x < NBC; x += stride) counts[x] = 0u;
  if (i < 8) lacc[i] = 0.f;
}

// ---------------------------------------------------------------- f [B,C,J,L] -> pm [p][c]
__global__ void k_f2pm(const float* __restrict__ f, float* __restrict__ pm) {
  __shared__ float t[64][65];
  int tid = threadIdx.x;
  int px0 = blockIdx.x * 64, c0 = blockIdx.y * 64;
  int b = px0 >> 12, y = (px0 >> 8) & 15, x0 = px0 & 255;
#pragma unroll
  for (int it = 0; it < 4; ++it) {
    int slot = it * 256 + tid;
    int c = slot >> 4, q = (slot & 15) * 4;
    float4 v = *(const float4*)(f + (((size_t)(b * 256 + c0 + c)) * 16 + y) * 256 + x0 + q);
    t[c][q] = v.x; t[c][q + 1] = v.y; t[c][q + 2] = v.z; t[c][q + 3] = v.w;
  }
  __syncthreads();
#pragma unroll
  for (int it = 0; it < 4; ++it) {
    int slot = it * 256 + tid;
    int i = slot >> 4, q = (slot & 15) * 4;
    float4 v;
    v.x = t[q + 0][i]; v.y = t[q + 1][i]; v.z = t[q + 2][i]; v.w = t[q + 3][i];
    *(float4*)(pm + (size_t)(px0 + i) * 256 + c0 + q) = v;
  }
}

// ---------------------------------------------------------------- out = f - pm (transpose back)
__global__ void k_out(const float* __restrict__ f, const float* __restrict__ pm,
                      float* __restrict__ out) {
  __shared__ float t[64][65];
  int tid = threadIdx.x;
  int px0 = blockIdx.x * 64, c0 = blockIdx.y * 64;
  int b = px0 >> 12, y = (px0 >> 8) & 15, x0 = px0 & 255;
#pragma unroll
  for (int it = 0; it < 4; ++it) {
    int slot = it * 256 + tid;
    int i = slot >> 4, q = (slot & 15) * 4;
    float4 v = *(const float4*)(pm + (size_t)(px0 + i) * 256 + c0 + q);
    t[q + 0][i] = v.x; t[q + 1][i] = v.y; t[q + 2][i] = v.z; t[q + 3][i] = v.w;
  }
  __syncthreads();
#pragma unroll
  for (int it = 0; it < 4; ++it) {
    int slot = it * 256 + tid;
    int c = slot >> 4, q = (slot & 15) * 4;
    size_t g = (((size_t)(b * 256 + c0 + c)) * 16 + y) * 256 + x0 + q;
    float4 fv = *(const float4*)(f + g);
    float4 o;
    o.x = fv.x - t[c][q + 0]; o.y = fv.y - t[c][q + 1];
    o.z = fv.z - t[c][q + 2]; o.w = fv.w - t[c][q + 3];
    *(float4*)(out + g) = o;
  }
}

// ---------------------------------------------------------------- cb_sq
__global__ void k_cbsq(const float* __restrict__ cb, float* __restrict__ cbsq) {
  int k = blockIdx.x * blockDim.x + threadIdx.x;
  if (k >= NBC) return;
  const float4* row = (const float4*)(cb + (size_t)k * CC);
  float s = 0.f;
  for (int i = 0; i < CC / 4; ++i) {
    float4 v = row[i];
    s += v.x * v.x + v.y * v.y + v.z * v.z + v.w * v.w;
  }
  cbsq[k] = s;
}

// ---------------------------------------------------------------- fp32 -> split bf16 (elementwise x4)
__global__ void k_split(const float* __restrict__ src, u16* __restrict__ hi,
                        u16* __restrict__ lo, int n) {
  int i = (blockIdx.x * 256 + threadIdx.x) * 4;
  if (i >= n) return;
  float4 v = *(const float4*)(src + i);
  ushort4 h, l;
  h.x = bf16h(v.x); l.x = bf16h(v.x - bf16f(h.x));
  h.y = bf16h(v.y); l.y = bf16h(v.y - bf16f(h.y));
  h.z = bf16h(v.z); l.z = bf16h(v.z - bf16f(h.z));
  h.w = bf16h(v.w); l.w = bf16h(v.w - bf16f(h.w));
  *(ushort4*)(hi + i) = h;
  *(ushort4*)(lo + i) = l;
}

// ---------------------------------------------------------------- weight split/transpose prep
// Whi/Wlo[(phi*9+s)*256 + co][ci] bf16
__global__ void k_wprep(const float* __restrict__ pw, u16* __restrict__ Whi,
                        u16* __restrict__ Wlo) {
  int bx = blockIdx.x;          // (phi*9+s)*256 + co
  int co = bx & 255;
  int ps = bx >> 8;             // phi*9+s
  int phi = ps / 9, s = ps % 9;
  int ci = threadIdx.x;
  float v = pw[(((size_t)(phi * 256 + co)) * 256 + ci) * 9 + s];
  u16 h = bf16h(v);
  Whi[(size_t)bx * 256 + ci] = h;
  Wlo[(size_t)bx * 256 + ci] = bf16h(v - bf16f(h));
}

// ---------------------------------------------------------------- pooling (pixel-major), 2-phase
__global__ void k_poolpart(const float* __restrict__ pm, float* __restrict__ part,
                           int sn, int tn, int pj, int wl, int K, int ppk) {
  int n = blockIdx.x, kk = blockIdx.y, c = threadIdx.x;
  int b = n / (sn * tn);
  int s = (n / tn) % sn;
  int t = n % tn;
  float acc = 0.f;
  for (int q = kk * ppk; q < (kk + 1) * ppk; ++q) {
    int yy = s * pj + q / wl;
    int xx = t * wl + q % wl;
    size_t p = (size_t)b * 4096 + (size_t)yy * 256 + xx;
    acc += pm[p * 256 + c];
  }
  part[((size_t)n * K + kk) * 256 + c] = acc;
}

__global__ void k_poolfin(const float* __restrict__ part, float* __restrict__ rows,
                          int K, float inv) {
  int n = blockIdx.x, c = threadIdx.x;
  float s = 0.f;
  for (int kk = 0; kk < K; ++kk) s += part[((size_t)n * K + kk) * 256 + c];
  rows[(size_t)n * 256 + c] = s * inv;
}

// ---------------------------------------------------------------- MFMA codebook argmin
// Wave: 32 queries resident in A-frags (hi/lo, full K=256). Codes streamed 64/tile
// through LDS (rows padded to 264 u16). d = cbsq - 2*dot via 3-term split-bf16 MFMA.
// C-layout: row=query(quad*4+r), col=code(lane&15). Packed-key min, atomicMin finish.
#define MS_QB 128
__global__ __launch_bounds__(256, 2) void k_msearch(
    const u16* __restrict__ Qhi, const u16* __restrict__ Qlo,
    const u16* __restrict__ CBhi, const u16* __restrict__ CBlo,
    const float* __restrict__ cbsq, unsigned long long* __restrict__ bkey,
    int nQ, int tilesPerBlock) {
  __shared__ __align__(16) u16 Bh[64 * 264];
  __shared__ __align__(16) u16 Bl[64 * 264];
  __shared__ float sq[64];
  int tid = threadIdx.x;
  int wid = tid >> 6, lane = tid & 63;
  int lm = lane & 15, quad = lane >> 4;
  int qw = blockIdx.x * MS_QB + wid * 32;
  int t0 = blockIdx.y * tilesPerBlock;

  short8 qh[2][8], ql[2][8];
#pragma unroll
  for (int mt = 0; mt < 2; ++mt)
#pragma unroll
    for (int kc = 0; kc < 8; ++kc) {
      size_t a = (size_t)(qw + mt * 16 + lm) * 256 + kc * 32 + quad * 8;
      qh[mt][kc] = *(const short8*)(Qhi + a);
      ql[mt][kc] = *(const short8*)(Qlo + a);
    }

  unsigned long long rk[2][4];
#pragma unroll
  for (int mt = 0; mt < 2; ++mt)
#pragma unroll
    for (int r = 0; r < 4; ++r) rk[mt][r] = 0xFFFFFFFFFFFFFFFFull;

  for (int t = 0; t < tilesPerBlock; ++t) {
    int n0 = (t0 + t) * 64;
    __syncthreads();
#pragma unroll
    for (int it = 0; it < 8; ++it) {
      int slot = tid + it * 256;
      int n = slot >> 5, ks = (slot & 31) * 8;
      *(uint4*)&Bh[n * 264 + ks] = *(const uint4*)(CBhi + (size_t)(n0 + n) * 256 + ks);
      *(uint4*)&Bl[n * 264 + ks] = *(const uint4*)(CBlo + (size_t)(n0 + n) * 256 + ks);
    }
    if (tid < 64) sq[tid] = cbsq[n0 + tid];
    __syncthreads();
#pragma unroll
    for (int nt = 0; nt < 4; ++nt) {
      floatx4 acc0 = {0.f, 0.f, 0.f, 0.f}, acc1 = {0.f, 0.f, 0.f, 0.f};
#pragma unroll
      for (int kc = 0; kc < 8; ++kc) {
        short8 bh = *(const short8*)&Bh[(nt * 16 + lm) * 264 + kc * 32 + quad * 8];
        short8 bl = *(const short8*)&Bl[(nt * 16 + lm) * 264 + kc * 32 + quad * 8];
        acc0 = __builtin_amdgcn_mfma_f32_16x16x32_bf16(qh[0][kc], bh, acc0, 0, 0, 0);
        acc0 = __builtin_amdgcn_mfma_f32_16x16x32_bf16(qh[0][kc], bl, acc0, 0, 0, 0);
        acc0 = __builtin_amdgcn_mfma_f32_16x16x32_bf16(ql[0][kc], bh, acc0, 0, 0, 0);
        acc1 = __builtin_amdgcn_mfma_f32_16x16x32_bf16(qh[1][kc], bh, acc1, 0, 0, 0);
        acc1 = __builtin_amdgcn_mfma_f32_16x16x32_bf16(qh[1][kc], bl, acc1, 0, 0, 0);
        acc1 = __builtin_amdgcn_mfma_f32_16x16x32_bf16(ql[1][kc], bh, acc1, 0, 0, 0);
      }
      uint32_t code = (uint32_t)(n0 + nt * 16 + lm);
      float csq = sq[nt * 16 + lm];
#pragma unroll
      for (int r = 0; r < 4; ++r) {
        float d0 = csq - 2.f * acc0[r];
        float d1 = csq - 2.f * acc1[r];
        unsigned long long k0 = ((unsigned long long)ord_f32(d0) << 32) | code;
        unsigned long long k1 = ((unsigned long long)ord_f32(d1) << 32) | code;
        if (k0 < rk[0][r]) rk[0][r] = k0;
        if (k1 < rk[1][r]) rk[1][r] = k1;
      }
    }
  }

#pragma unroll
  for (int mt = 0; mt < 2; ++mt)
#pragma unroll
    for (int r = 0; r < 4; ++r) {
      unsigned long long k = rk[mt][r];
#pragma unroll
      for (int off = 1; off <= 8; off <<= 1) {
        uint32_t lo = (uint32_t)k, hi = (uint32_t)(k >> 32);
        uint32_t olo = __shfl_xor(lo, off, 64);
        uint32_t ohi = __shfl_xor(hi, off, 64);
        unsigned long long ok = ((unsigned long long)ohi << 32) | olo;
        if (ok < k) k = ok;
      }
      if (lm == 0) {
        int q = qw + mt * 16 + quad * 4 + r;
        if (q < nQ) atomicMin(&bkey[q], k);
      }
    }
}

// ---------------------------------------------------------------- gather + bicubic up -> split bf16 H
__global__ void k_upgather(const unsigned long long* __restrict__ bkey,
                           const float* __restrict__ cb,
                           u16* __restrict__ Hhi, u16* __restrict__ Hlo,
                           int sn, int tn, int last) {
  __shared__ int sidx[8][16];
  __shared__ float swgt[8][16];
  int tid = threadIdx.x;
  int p0 = blockIdx.x * 8;
  if (!last) {
    if (tid < 128) {
      int pp = tid >> 4, tap = tid & 15;
      int aa = tap >> 2, ee = tap & 3;
      int p = p0 + pp;
      int b = p >> 12, y = (p >> 8) & 15, x = p & 255;
      float cj = (y + 0.5f) * ((float)sn / 16.f) - 0.5f;
      float fj = floorf(cj); float tj = cj - fj; int ij = (int)fj;
      float wj = cubw(tj - (float)(aa - 1));
      int xj = min(max(ij + aa - 1, 0), sn - 1);
      float cl = (x + 0.5f) * ((float)tn / 256.f) - 0.5f;
      float fl = floorf(cl); float tl = cl - fl; int il = (int)fl;
      float wle = cubw(tl - (float)(ee - 1));
      int xl = min(max(il + ee - 1, 0), tn - 1);
      int n = (b * sn + xj) * tn + xl;
      sidx[pp][tap] = (int)((uint32_t)bkey[n] & (NBC - 1));
      swgt[pp][tap] = wj * wle;
    }
  } else {
    if (tid < 8) sidx[tid][0] = (int)((uint32_t)bkey[p0 + tid] & (NBC - 1));
  }
  __syncthreads();
  int c = tid;
  for (int pp = 0; pp < 8; ++pp) {
    float val;
    if (last) {
      val = cb[(size_t)sidx[pp][0] * 256 + c];
    } else {
      val = 0.f;
#pragma unroll
      for (int tap = 0; tap < 16; ++tap)
        val += swgt[pp][tap] * cb[(size_t)sidx[pp][tap] * 256 + c];
    }
    u16 h = bf16h(val);
    u16 l = bf16h(val - bf16f(h));
    size_t g = (size_t)(p0 + pp) * 256 + c;
    Hhi[g] = h;
    Hlo[g] = l;
  }
}

// ---------------------------------------------------------------- conv3x3 as split-bf16 MFMA implicit GEMM
#define CO_T 64
#define X_T 128
__global__ __launch_bounds__(256) void k_conv(
    const u16* __restrict__ Hhi, const u16* __restrict__ Hlo,
    const u16* __restrict__ Wh, const u16* __restrict__ Wl,
    const float* __restrict__ bias, float* __restrict__ pm,
    float* __restrict__ lacc, int si) {
  __shared__ __align__(16) u16 Ah[128 * 40];
  __shared__ __align__(16) u16 Al[128 * 40];
  __shared__ __align__(16) u16 Bh[128 * 40];
  __shared__ __align__(16) u16 Bl[128 * 40];
  __shared__ float redl[4];
  int tid = threadIdx.x;
  int mt = blockIdx.x >> 1, nt = blockIdx.x & 1;
  int px0 = mt * 128;
  int b4096 = px0 & ~4095;
  int y = (px0 >> 8) & 15;
  int x0 = px0 & 255;
  int co0 = nt * 128;
  int wid = tid >> 6, lane = tid & 63;
  int wm = wid & 1, wn = wid >> 1;
  int lm = lane & 15, quad = lane >> 4, k0 = quad * 8;

  floatx4 acc[4][4];
#pragma unroll
  for (int i = 0; i < 4; ++i)
#pragma unroll
    for (int j = 0; j < 4; ++j) acc[i][j] = (floatx4){0.f, 0.f, 0.f, 0.f};

  for (int s = 0; s < 9; ++s) {
    int dy = s / 3 - 1, dx = s % 3 - 1;
    int ys = y + dy;
    if (ys < 0 || ys > 15) continue;       // wave-uniform skip
    const u16* wbh = Wh + (size_t)s * 65536;
    const u16* wbl = Wl + (size_t)s * 65536;
    for (int ci0 = 0; ci0 < 256; ci0 += 32) {
      __syncthreads();
#pragma unroll
      for (int it = 0; it < 2; ++it) {
        int slot = tid + it * 256;
        int pxl = slot >> 2, ch = (slot & 3) * 8;
        int xs = x0 + pxl + dx;
        uint4 vh = {0, 0, 0, 0}, vl = {0, 0, 0, 0};
        if (xs >= 0 && xs < 256) {
          size_t g = ((size_t)(b4096 + ys * 256 + xs)) * 256 + ci0 + ch;
          vh = *(const uint4*)(Hhi + g);
          vl = *(const uint4*)(Hlo + g);
        }
        *(uint4*)&Ah[pxl * 40 + ch] = vh;
        *(uint4*)&Al[pxl * 40 + ch] = vl;
        size_t gw = (size_t)(co0 + pxl) * 256 + ci0 + ch;
        *(uint4*)&Bh[pxl * 40 + ch] = *(const uint4*)(wbh + gw);
        *(uint4*)&Bl[pxl * 40 + ch] = *(const uint4*)(wbl + gw);
      }
      __syncthreads();
      short8 ah[4], al[4], bh[4], bl[4];
#pragma unroll
      for (int mi = 0; mi < 4; ++mi) {
        int r = wm * 64 + mi * 16 + lm;
        ah[mi] = *(const short8*)&Ah[r * 40 + k0];
        al[mi] = *(const short8*)&Al[r * 40 + k0];
      }
#pragma unroll
      for (int ni = 0; ni < 4; ++ni) {
        int r = wn * 64 + ni * 16 + lm;
        bh[ni] = *(const short8*)&Bh[r * 40 + k0];
        bl[ni] = *(const short8*)&Bl[r * 40 + k0];
      }
#pragma unroll
      for (int mi = 0; mi < 4; ++mi)
#pragma unroll
        for (int ni = 0; ni < 4; ++ni) {
          acc[mi][ni] = __builtin_amdgcn_mfma_f32_16x16x32_bf16(ah[mi], bh[ni], acc[mi][ni], 0, 0, 0);
          acc[mi][ni] = __builtin_amdgcn_mfma_f32_16x16x32_bf16(ah[mi], bl[ni], acc[mi][ni], 0, 0, 0);
          acc[mi][ni] = __builtin_amdgcn_mfma_f32_16x16x32_bf16(al[mi], bh[ni], acc[mi][ni], 0, 0, 0);
        }
    }
  }

  float lsum = 0.f;
#pragma unroll
  for (int mi = 0; mi < 4; ++mi) {
#pragma unroll
    for (int ni = 0; ni < 4; ++ni) {
      int co = co0 + wn * 64 + ni * 16 + lm;
      float bv = bias[co];
#pragma unroll
      for (int r = 0; r < 4; ++r) {
        int px = px0 + wm * 64 + mi * 16 + quad * 4 + r;
        size_t g = (size_t)px * 256 + co;
        float h = bf16f(Hhi[g]) + bf16f(Hlo[g]);
        float o = 0.5f * h + 0.5f * (acc[mi][ni][r] + bv);
        float fr = pm[g] - o;
        pm[g] = fr;
        lsum += fr * fr;
      }
    }
  }
  for (int off = 32; off; off >>= 1) lsum += __shfl_xor(lsum, off, 64);
  if (lane == 0) redl[wid] = lsum;
  __syncthreads();
  if (tid == 0) atomicAdd(&lacc[si], redl[0] + redl[1] + redl[2] + redl[3]);
}

// ---------------------------------------------------------------- histogram
__global__ void k_hist(const unsigned long long* __restrict__ bkey,
                       uint32_t* __restrict__ counts) {
  int i = blockIdx.x * 256 + threadIdx.x;
  if (i < NTOT) atomicAdd(&counts[(uint32_t)bkey[i] & (NBC - 1)], 1u);
}

// ---------------------------------------------------------------- loss + perplexity scalars
__global__ void k_scalars(const uint32_t* __restrict__ counts,
                          const float* __restrict__ lacc,
                          float* __restrict__ out) {
  __shared__ float red[4];
  int tid = threadIdx.x;
  float s = 0.f;
  for (int i = tid; i < NBC; i += 256) {
    float p = (float)counts[i] * (1.0f / (float)NTOT);
    s += p * logf(p + 1e-7f);
  }
  for (int off = 32; off; off >>= 1) s += __shfl_xor(s, off, 64);
  if ((tid & 63) == 0) red[tid >> 6] = s;
  __syncthreads();
  if (tid == 0) {
    float ent = red[0] + red[1] + red[2] + red[3];
    out[NEL + 1] = expf(-ent);
    float l = 0.f;
    for (int i = 0; i < 5; ++i) l += lacc[i];
    out[NEL] = l * (1.0f / (float)NEL / 5.0f);
  }
}

extern "C" void kernel_launch(void* const* d_in, const int* in_sizes, int n_in,
                              void* d_out, int out_size, void* d_ws, size_t ws_size,
                              hipStream_t stream) {
  const float* f  = (const float*)d_in[0];
  const float* cb = (const float*)d_in[1];
  const float* pw = (const float*)d_in[2];
  const float* pb = (const float*)d_in[3];
  float* out = (float*)d_out;

  char* ws = (char*)d_ws;
  size_t off = 0;
  auto alloc = [&](size_t bytes) {
    void* p = ws + off;
    off += (bytes + 255) & ~(size_t)255;
    return p;
  };
  float* pm    = (float*)alloc((size_t)NEL * 4);            // f_rest, pixel-major [p][c]
  u16*   Hhi   = (u16*)alloc((size_t)NEL * 2);
  u16*   Hlo   = (u16*)alloc((size_t)NEL * 2);
  float* rows  = (float*)alloc((size_t)8192 * 256 * 4);
  float* part  = (float*)alloc((size_t)8192 * 256 * 4);
  u16*   Whi   = (u16*)alloc((size_t)4 * 9 * 65536 * 2);
  u16*   Wlo   = (u16*)alloc((size_t)4 * 9 * 65536 * 2);
  u16*   Qhi   = (u16*)alloc((size_t)NPIX * 256 * 2);
  u16*   Qlo   = (u16*)alloc((size_t)NPIX * 256 * 2);
  u16*   CBhi  = (u16*)alloc((size_t)NBC * 256 * 2);
  u16*   CBlo  = (u16*)alloc((size_t)NBC * 256 * 2);
  float* cbsq  = (float*)alloc((size_t)NBC * 4);
  unsigned long long* bkey = (unsigned long long*)alloc((size_t)NTOT * 8);
  uint32_t* counts = (uint32_t*)alloc((size_t)NBC * 4);
  float* lacc = (float*)alloc(8 * 4);

  k_init<<<256, 256, 0, stream>>>(bkey, counts, lacc);
  k_f2pm<<<dim3(NPIX / 64, 4), 256, 0, stream>>>(f, pm);
  k_cbsq<<<NBC / 256, 256, 0, stream>>>(cb, cbsq);
  k_split<<<(NBC * 256) / 1024, 256, 0, stream>>>(cb, CBhi, CBlo, NBC * 256);
  k_wprep<<<4 * 9 * 256, 256, 0, stream>>>(pw, Whi, Wlo);

  const int SNs[5]   = {1, 2, 4, 8, 16};
  const int TNs[5]   = {4, 16, 64, 128, 256};
  const int PHI[5]   = {0, 1, 1, 2, 3};
  const int KCH[5]   = {32, 64, 16, 8, 2};   // code-chunk grid dim
  const int Ks[5]    = {16, 8, 2, 1, 1};
  int offs = 0;
  for (int si = 0; si < 5; ++si) {
    int sn = SNs[si], tn = TNs[si];
    int N = BB * sn * tn;
    int pj = JJ / sn, wl = LL / tn;
    unsigned long long* bk = bkey + offs;
    const float* qsrc;
    if (si < 4) {
      int K = Ks[si], npx = pj * wl;
      k_poolpart<<<dim3(N, K), 256, 0, stream>>>(pm, part, sn, tn, pj, wl, K, npx / K);
      k_poolfin<<<N, 256, 0, stream>>>(part, rows, K, 1.0f / (float)npx);
      qsrc = rows;
    } else {
      qsrc = pm;   // pixel-major residual IS the query matrix
    }
    k_split<<<(N * 256 + 1023) / 1024, 256, 0, stream>>>(qsrc, Qhi, Qlo, N * 256);
    int qtiles = (N + MS_QB - 1) / MS_QB;
    int tpb = (NBC / 64) / KCH[si];
    dim3 g(qtiles, KCH[si]);
    k_msearch<<<g, 256, 0, stream>>>(Qhi, Qlo, CBhi, CBlo, cbsq, bk, N, tpb);
    k_upgather<<<NPIX / 8, 256, 0, stream>>>(bk, cb, Hhi, Hlo, sn, tn, si == 4);
    k_conv<<<512, 256, 0, stream>>>(Hhi, Hlo,
                                    Whi + (size_t)PHI[si] * 9 * 65536,
                                    Wlo + (size_t)PHI[si] * 9 * 65536,
                                    pb + (size_t)PHI[si] * 256, pm, lacc, si);
    offs += N;
  }
  k_hist<<<(NTOT + 255) / 256, 256, 0, stream>>>(bkey, counts);
  k_out<<<dim3(NPIX / 64, 4), 256, 0, stream>>>(f, pm, out);
  k_scalars<<<1, 256, 0, stream>>>(counts, lacc, out);
}